// Round 3
// baseline (1709.815 us; speedup 1.0000x reference)
//
#include <hip/hip_runtime.h>
#include <hip/hip_fp16.h>

#define NB   256
#define TT   1024
#define II   64
#define HH1  128
#define GG1  512
#define HH2  64
#define GG2  256
#define NT   1024

typedef _Float16 f16;
typedef _Float16 f16x2 __attribute__((ext_vector_type(2)));

union F4 { float4 f; f16x2 h[4]; };

__device__ __forceinline__ float rcp_fast(float x){
    float r; asm("v_rcp_f32 %0, %1" : "=v"(r) : "v"(x)); return r;
}
__device__ __forceinline__ float sigm(float x){
    return rcp_fast(1.0f + __expf(-x));
}
__device__ __forceinline__ float tanh_f(float x){
    x = fminf(10.0f, fmaxf(-10.0f, x));
    float e = __expf(2.0f * x);
    return (e - 1.0f) * rcp_fast(e + 1.0f);
}
__device__ __forceinline__ f16x2 pack2(float a, float b){
    f16x2 r; r.x = (f16)a; r.y = (f16)b; return r;
}
__device__ __forceinline__ float dot2(f16x2 a, f16x2 b, float c){
#if __has_builtin(__builtin_amdgcn_fdot2)
    return __builtin_amdgcn_fdot2(a, b, c, false);
#else
    return fmaf((float)a.x, (float)b.x, fmaf((float)a.y, (float)b.y, c));
#endif
}

// act layout (f16): [ x(64) | h1(128) | h2(64) ]  -> 256 f16 = 512 B
// L1 K-vector = act[0:192)   (x ++ h1), split in halves of 96
// L2 K-vector = act[64:256)  (h1 ++ h2), split in chunks of 48

__launch_bounds__(NT, 4)
__global__ void lstm_fused(const float* __restrict__ x,
                           const float* __restrict__ Wih1, const float* __restrict__ Whh1,
                           const float* __restrict__ bih1, const float* __restrict__ bhh1,
                           const float* __restrict__ Wih2, const float* __restrict__ Whh2,
                           const float* __restrict__ bih2, const float* __restrict__ bhh2,
                           const float* __restrict__ W1,   const float* __restrict__ b1,
                           const float* __restrict__ W2,   const float* __restrict__ b2,
                           float* __restrict__ out)
{
    __shared__ __align__(16) f16   act[256];
    __shared__ __align__(16) float g1p[2][GG1];   // L1 partial dots
    __shared__ __align__(16) float p2p[4][GG2];   // L2 partial dots
    __shared__ __align__(16) float headbuf[32];

    const int j   = threadIdx.x;        // 0..1023
    const int b   = blockIdx.x;
    const int g1i = j & 511;            // L1 gate row
    const int h1f = j >> 9;             // L1 K-half (0,1)
    const int g2i = j & 255;            // L2 gate row
    const int c2k = j >> 8;             // L2 K-chunk (0..3)

    // ---------- one-time: weights -> f16 pairs in VGPRs ----------
    // L1 slice for (g1i, h1f): half0 = Wih1 row (64) + Whh1 row [0:32);
    //                          half1 = Whh1 row [32:128).
    f16x2 w1r[48];
    if (h1f == 0){
        const float4* p = (const float4*)(Wih1 + g1i*II);
        #pragma unroll
        for (int q = 0; q < 16; ++q){
            float4 v = p[q];
            w1r[2*q]   = pack2(v.x, v.y);
            w1r[2*q+1] = pack2(v.z, v.w);
        }
        const float4* ph = (const float4*)(Whh1 + g1i*HH1);
        #pragma unroll
        for (int q = 0; q < 8; ++q){
            float4 v = ph[q];
            w1r[32+2*q]   = pack2(v.x, v.y);
            w1r[32+2*q+1] = pack2(v.z, v.w);
        }
    } else {
        const float4* ph = (const float4*)(Whh1 + g1i*HH1 + 32);
        #pragma unroll
        for (int q = 0; q < 24; ++q){
            float4 v = ph[q];
            w1r[2*q]   = pack2(v.x, v.y);
            w1r[2*q+1] = pack2(v.z, v.w);
        }
    }
    // L2 slice for (g2i, c2k): cat-row = [Wih2 row (128) ; Whh2 row (64)], take [48*c2k, +48)
    f16x2 w2r[24];
    #pragma unroll
    for (int q = 0; q < 24; ++q){
        int k0 = 48*c2k + 2*q;
        int k1 = k0 + 1;
        float va = (k0 < HH1) ? Wih2[g2i*HH1 + k0] : Whh2[g2i*HH2 + (k0 - HH1)];
        float vb = (k1 < HH1) ? Wih2[g2i*HH1 + k1] : Whh2[g2i*HH2 + (k1 - HH1)];
        w2r[q] = pack2(va, vb);
    }

    const float bias1 = (h1f == 0) ? (bih1[g1i] + bhh1[g1i]) : 0.0f;
    float b2i = 0.f, b2f = 0.f, b2g = 0.f, b2o = 0.f;
    if (j >= 128 && j < 192){
        int u = j - 128;
        b2i = bih2[u]         + bhh2[u];
        b2f = bih2[HH2+u]     + bhh2[HH2+u];
        b2g = bih2[2*HH2+u]   + bhh2[2*HH2+u];
        b2o = bih2[3*HH2+u]   + bhh2[3*HH2+u];
    }

    const float* xb = x + (size_t)b * TT * II;
    if (j < II)               act[j] = (f16)xb[j];   // x_0
    if (j >= II && j < 256)   act[j] = (f16)0.0f;    // h1 = h2 = 0
    float c1 = 0.0f, c2 = 0.0f;
    __syncthreads();

    const float4* af4 = (const float4*)act;

    for (int t = 0; t < TT; ++t){
        // wave 3 prefetches x_{t+1} (published in phase A)
        float xn = 0.0f;
        if (j >= 192 && j < 256){
            int tn = (t+1 < TT) ? (t+1) : (TT-1);
            xn = xb[tn*II + (j-192)];
        }

        // ---- Phase D: L1 dots (step t) + L2 dots (step t-1) ----
        float a0 = bias1, a1 = 0.f, a2 = 0.f, a3 = 0.f;
        {
            const float4* pa = af4 + 12*h1f;
            #pragma unroll
            for (int q = 0; q < 12; ++q){
                F4 u; u.f = pa[q];
                a0 = dot2(w1r[4*q+0], u.h[0], a0);
                a1 = dot2(w1r[4*q+1], u.h[1], a1);
                a2 = dot2(w1r[4*q+2], u.h[2], a2);
                a3 = dot2(w1r[4*q+3], u.h[3], a3);
            }
        }
        float s0 = 0.f, s1 = 0.f, s2 = 0.f, s3 = 0.f;
        {
            const float4* pb = af4 + 8 + 6*c2k;
            #pragma unroll
            for (int q = 0; q < 6; ++q){
                F4 u; u.f = pb[q];
                s0 = dot2(w2r[4*q+0], u.h[0], s0);
                s1 = dot2(w2r[4*q+1], u.h[1], s1);
                s2 = dot2(w2r[4*q+2], u.h[2], s2);
                s3 = dot2(w2r[4*q+3], u.h[3], s3);
            }
        }
        g1p[h1f][g1i] = (a0 + a1) + (a2 + a3);
        p2p[c2k][g2i] = (s0 + s1) + (s2 + s3);
        __syncthreads();

        // ---- Phase A: activations ----
        if (j < HH1){
            float gi = g1p[0][j]         + g1p[1][j];
            float gf = g1p[0][HH1+j]     + g1p[1][HH1+j];
            float gg = g1p[0][2*HH1+j]   + g1p[1][2*HH1+j];
            float go = g1p[0][3*HH1+j]   + g1p[1][3*HH1+j];
            float ii = sigm(gi), ff = sigm(gf), tg = tanh_f(gg), oo = sigm(go);
            c1 = ff*c1 + ii*tg;
            act[II + j] = (f16)(oo * tanh_f(c1));
        } else if (j < 192){
            if (t > 0){
                int u = j - 128;
                float vi = p2p[0][u]        + p2p[1][u]        + p2p[2][u]        + p2p[3][u]        + b2i;
                float vf = p2p[0][HH2+u]    + p2p[1][HH2+u]    + p2p[2][HH2+u]    + p2p[3][HH2+u]    + b2f;
                float vg = p2p[0][2*HH2+u]  + p2p[1][2*HH2+u]  + p2p[2][2*HH2+u]  + p2p[3][2*HH2+u]  + b2g;
                float vo = p2p[0][3*HH2+u]  + p2p[1][3*HH2+u]  + p2p[2][3*HH2+u]  + p2p[3][3*HH2+u]  + b2o;
                float ii = sigm(vi), ff = sigm(vf), tg = tanh_f(vg), oo = sigm(vo);
                c2 = ff*c2 + ii*tg;
                act[192 + u] = (f16)(oo * tanh_f(c2));
            }
        } else if (j < 256){
            act[j - 192] = (f16)xn;      // publish x_{t+1}
        }
        __syncthreads();
    }

    // ---- epilogue: L2 dots + activation for step TT-1 ----
    {
        float s0 = 0.f, s1 = 0.f, s2 = 0.f, s3 = 0.f;
        const float4* pb = af4 + 8 + 6*c2k;
        #pragma unroll
        for (int q = 0; q < 6; ++q){
            F4 u; u.f = pb[q];
            s0 = dot2(w2r[4*q+0], u.h[0], s0);
            s1 = dot2(w2r[4*q+1], u.h[1], s1);
            s2 = dot2(w2r[4*q+2], u.h[2], s2);
            s3 = dot2(w2r[4*q+3], u.h[3], s3);
        }
        p2p[c2k][g2i] = (s0 + s1) + (s2 + s3);
    }
    __syncthreads();
    if (j >= 128 && j < 192){
        int u = j - 128;
        float vi = p2p[0][u]        + p2p[1][u]        + p2p[2][u]        + p2p[3][u]        + b2i;
        float vf = p2p[0][HH2+u]    + p2p[1][HH2+u]    + p2p[2][HH2+u]    + p2p[3][HH2+u]    + b2f;
        float vg = p2p[0][2*HH2+u]  + p2p[1][2*HH2+u]  + p2p[2][2*HH2+u]  + p2p[3][2*HH2+u]  + b2g;
        float vo = p2p[0][3*HH2+u]  + p2p[1][3*HH2+u]  + p2p[2][3*HH2+u]  + p2p[3][3*HH2+u]  + b2o;
        float ii = sigm(vi), ff = sigm(vf), tg = tanh_f(vg), oo = sigm(vo);
        c2 = ff*c2 + ii*tg;
        act[192 + u] = (f16)(oo * tanh_f(c2));
    }
    __syncthreads();

    // ---- MLP head ----
    if (j < 32){
        float a = b1[j];
        const float* w = W1 + j*HH2;
        #pragma unroll
        for (int k = 0; k < HH2; ++k) a = fmaf(w[k], (float)act[192+k], a);
        headbuf[j] = sigm(a);
    }
    __syncthreads();
    if (j == 0){
        float a = b2[0];
        #pragma unroll
        for (int k = 0; k < 32; ++k) a = fmaf(W2[k], headbuf[k], a);
        out[b] = sigm(a);
    }
}

extern "C" void kernel_launch(void* const* d_in, const int* in_sizes, int n_in,
                              void* d_out, int out_size, void* d_ws, size_t ws_size,
                              hipStream_t stream)
{
    (void)in_sizes; (void)n_in; (void)d_ws; (void)ws_size; (void)out_size;
    lstm_fused<<<NB, NT, 0, stream>>>(
        (const float*)d_in[0],
        (const float*)d_in[1], (const float*)d_in[2],
        (const float*)d_in[3], (const float*)d_in[4],
        (const float*)d_in[5], (const float*)d_in[6],
        (const float*)d_in[7], (const float*)d_in[8],
        (const float*)d_in[9], (const float*)d_in[10],
        (const float*)d_in[11], (const float*)d_in[12],
        (float*)d_out);
}

// Round 5
// 1125.834 us; speedup vs baseline: 1.5187x; 1.5187x over previous
//
#include <hip/hip_runtime.h>
#include <hip/hip_fp16.h>

#define NB   256
#define TT   1024
#define II   64
#define NT   768

typedef _Float16 f16;
typedef _Float16 hf8 __attribute__((ext_vector_type(8)));
typedef float    ff4 __attribute__((ext_vector_type(4)));

__device__ __forceinline__ float rcp_fast(float x){
    float r; asm("v_rcp_f32 %0, %1" : "=v"(r) : "v"(x)); return r;
}
__device__ __forceinline__ float sigm(float x){
    return rcp_fast(1.0f + __expf(-x));
}
__device__ __forceinline__ float tanh_f(float x){
    x = fminf(10.0f, fmaxf(-10.0f, x));
    float e = __expf(2.0f * x);
    return (e - 1.0f) * rcp_fast(e + 1.0f);
}

// Tiles: 48 M-tiles of 16 gate-rows. Tiles 0-31: L1 (512 rows, K=192 over
// [x(64);h1(128)]). Tiles 32-47: L2 (256 rows, K=192 over [h1(128);h2(64)]).
// act buffer (f16, 256): [ x(64) | h1(128) | h2(64) ].  L1 kbase=0, L2 kbase=64.
// A-frag (16x16x32): lane holds row=lane&15, k=(lane>>4)*8+q (k-placement is
// self-consistent between A and B, so the dot pairs W/act at identical k even
// if the HW mapping differs from this guess).
// B-frag: every lane in a (lane>>4)-group reads the same 8 f16 -> all 16 B
// columns identical -> all C columns identical (mapping-robust by construction).
// C/D: col=lane&15, row=(lane>>4)*4+reg  [m89 verified].

__launch_bounds__(NT, 3)
__global__ void lstm_mfma(const float* __restrict__ x,
                          const float* __restrict__ Wih1, const float* __restrict__ Whh1,
                          const float* __restrict__ bih1, const float* __restrict__ bhh1,
                          const float* __restrict__ Wih2, const float* __restrict__ Whh2,
                          const float* __restrict__ bih2, const float* __restrict__ bhh2,
                          const float* __restrict__ W1,   const float* __restrict__ b1,
                          const float* __restrict__ W2,   const float* __restrict__ b2,
                          float* __restrict__ out)
{
    __shared__ __align__(16) f16   act[2][256];
    __shared__ __align__(16) float g[768];      // preacts: L1 rows 0-511, L2 rows 512-767
    __shared__ float headbuf[32];

    const int j    = threadIdx.x;      // 0..767
    const int b    = blockIdx.x;
    const int wave = j >> 6;           // 0..11
    const int lane = j & 63;
    const int row  = lane & 15;
    const int kg   = lane >> 4;        // 0..3
    const bool l2w = (wave >= 8);
    const int kbase = l2w ? 64 : 0;

    // ---------- one-time: A fragments (f16 weights), bias, write bases ----------
    hf8 A[4][6];
    ff4 bias[4];
    int rb[4];                          // full C-row base (includes kg*4)
    #pragma unroll
    for (int i = 0; i < 4; ++i){
        const int tau = 4*wave + i;
        #pragma unroll
        for (int kt = 0; kt < 6; ++kt){
            const int k = 32*kt + kg*8;
            const float* src;
            if (!l2w){
                const int G = 16*tau + row;
                src = (k < 64) ? (Wih1 + G*64 + k) : (Whh1 + G*128 + (k - 64));
            } else {
                const int G = 16*(tau - 32) + row;
                src = (k < 128) ? (Wih2 + G*128 + k) : (Whh2 + G*64 + (k - 128));
            }
            float4 v0 = *(const float4*)src;
            float4 v1 = *(const float4*)(src + 4);
            hf8 a;
            a[0]=(f16)v0.x; a[1]=(f16)v0.y; a[2]=(f16)v0.z; a[3]=(f16)v0.w;
            a[4]=(f16)v1.x; a[5]=(f16)v1.y; a[6]=(f16)v1.z; a[7]=(f16)v1.w;
            A[i][kt] = a;
        }
        if (!l2w){
            const int Gb = 16*tau + kg*4;
            rb[i] = Gb;
            #pragma unroll
            for (int r = 0; r < 4; ++r) bias[i][r] = bih1[Gb+r] + bhh1[Gb+r];
        } else {
            const int Gb = 16*(tau - 32) + kg*4;
            rb[i] = 512 + Gb;
            #pragma unroll
            for (int r = 0; r < 4; ++r) bias[i][r] = bih2[Gb+r] + bhh2[Gb+r];
        }
    }

    const float* xb = x + (size_t)b * TT * II;

    // init act[0]: x_0, h1=0, h2=0
    if (j < II)                act[0][j] = (f16)xb[j];
    else if (j < 256)          act[0][j] = (f16)0.0f;
    float c1 = 0.0f, c2 = 0.0f;
    __syncthreads();

    int cur = 0;
    for (int t = 0; t < TT; ++t){
        const f16* Ac = act[cur];
        f16*       An = act[cur ^ 1];

        // wave 3 (threads 192-255) prefetches x_{t+1}
        float xn = 0.0f;
        if (j >= 192 && j < 256){
            int tn = (t + 1 < TT) ? (t + 1) : (TT - 1);
            xn = xb[tn*II + (j - 192)];
        }

        // ---- MFMA phase: preacts for L1(step t) and L2(step t-1) ----
        ff4 acc0 = bias[0], acc1 = bias[1], acc2 = bias[2], acc3 = bias[3];
        #pragma unroll
        for (int kt = 0; kt < 6; ++kt){
            hf8 bf = *(const hf8*)(Ac + kbase + 32*kt + kg*8);
            acc0 = __builtin_amdgcn_mfma_f32_16x16x32_f16(A[0][kt], bf, acc0, 0, 0, 0);
            acc1 = __builtin_amdgcn_mfma_f32_16x16x32_f16(A[1][kt], bf, acc1, 0, 0, 0);
            acc2 = __builtin_amdgcn_mfma_f32_16x16x32_f16(A[2][kt], bf, acc2, 0, 0, 0);
            acc3 = __builtin_amdgcn_mfma_f32_16x16x32_f16(A[3][kt], bf, acc3, 0, 0, 0);
        }
        if ((lane & 15) == 0){
            *(ff4*)&g[rb[0]] = acc0;
            *(ff4*)&g[rb[1]] = acc1;
            *(ff4*)&g[rb[2]] = acc2;
            *(ff4*)&g[rb[3]] = acc3;
        }
        if (j >= 192 && j < 256) An[j - 192] = (f16)xn;   // publish x_{t+1}
        __syncthreads();                                   // g ready

        // ---- activation phase ----
        if (j < 128){                         // h1 unit j (step t)
            float ii = sigm(g[j]);
            float ff = sigm(g[128 + j]);
            float tg = tanh_f(g[256 + j]);
            float oo = sigm(g[384 + j]);
            c1 = ff*c1 + ii*tg;
            An[II + j] = (f16)(oo * tanh_f(c1));
        } else if (j < 192){                  // h2 unit u (step t-1)
            const int u = j - 128;
            if (t > 0){
                float ii = sigm(g[512 + u]);
                float ff = sigm(g[576 + u]);
                float tg = tanh_f(g[640 + u]);
                float oo = sigm(g[704 + u]);
                c2 = ff*c2 + ii*tg;
                An[192 + u] = (f16)(oo * tanh_f(c2));
            } else {
                An[192 + u] = (f16)0.0f;      // h2_{-1} = 0
            }
        }
        __syncthreads();                      // act[next] complete
        cur ^= 1;
    }

    // ---- epilogue: L2 step TT-1 (needs h1_{TT-1}, h2_{TT-2}, both in act[cur]) ----
    {
        const f16* Ac = act[cur];
        if (l2w){
            ff4 acc0 = bias[0], acc1 = bias[1], acc2 = bias[2], acc3 = bias[3];
            #pragma unroll
            for (int kt = 0; kt < 6; ++kt){
                hf8 bf = *(const hf8*)(Ac + kbase + 32*kt + kg*8);
                acc0 = __builtin_amdgcn_mfma_f32_16x16x32_f16(A[0][kt], bf, acc0, 0, 0, 0);
                acc1 = __builtin_amdgcn_mfma_f32_16x16x32_f16(A[1][kt], bf, acc1, 0, 0, 0);
                acc2 = __builtin_amdgcn_mfma_f32_16x16x32_f16(A[2][kt], bf, acc2, 0, 0, 0);
                acc3 = __builtin_amdgcn_mfma_f32_16x16x32_f16(A[3][kt], bf, acc3, 0, 0, 0);
            }
            if ((lane & 15) == 0){
                *(ff4*)&g[rb[0]] = acc0;
                *(ff4*)&g[rb[1]] = acc1;
                *(ff4*)&g[rb[2]] = acc2;
                *(ff4*)&g[rb[3]] = acc3;
            }
        }
    }
    __syncthreads();
    if (j >= 128 && j < 192){
        const int u = j - 128;
        float ii = sigm(g[512 + u]);
        float ff = sigm(g[576 + u]);
        float tg = tanh_f(g[640 + u]);
        float oo = sigm(g[704 + u]);
        c2 = ff*c2 + ii*tg;
        act[cur ^ 1][192 + u] = (f16)(oo * tanh_f(c2));
    }
    __syncthreads();

    // ---- MLP head ----
    if (j < 32){
        float a = b1[j];
        const float* w = W1 + j*64;
        #pragma unroll
        for (int k = 0; k < 64; ++k) a = fmaf(w[k], (float)act[cur ^ 1][192 + k], a);
        headbuf[j] = sigm(a);
    }
    __syncthreads();
    if (j == 0){
        float a = b2[0];
        #pragma unroll
        for (int k = 0; k < 32; ++k) a = fmaf(W2[k], headbuf[k], a);
        out[b] = sigm(a);
    }
}

extern "C" void kernel_launch(void* const* d_in, const int* in_sizes, int n_in,
                              void* d_out, int out_size, void* d_ws, size_t ws_size,
                              hipStream_t stream)
{
    (void)in_sizes; (void)n_in; (void)d_ws; (void)ws_size; (void)out_size;
    lstm_mfma<<<NB, NT, 0, stream>>>(
        (const float*)d_in[0],
        (const float*)d_in[1], (const float*)d_in[2],
        (const float*)d_in[3], (const float*)d_in[4],
        (const float*)d_in[5], (const float*)d_in[6],
        (const float*)d_in[7], (const float*)d_in[8],
        (const float*)d_in[9], (const float*)d_in[10],
        (const float*)d_in[11], (const float*)d_in[12],
        (float*)d_out);
}

// Round 6
// 967.649 us; speedup vs baseline: 1.7670x; 1.1635x over previous
//
#include <hip/hip_runtime.h>
#include <hip/hip_fp16.h>

#define NB   256
#define TT   1024
#define II   64
#define NT   768

typedef _Float16 f16;
typedef _Float16 hf8 __attribute__((ext_vector_type(8)));
typedef float    ff4 __attribute__((ext_vector_type(4)));

__device__ __forceinline__ float rcp_fast(float x){
    float r; asm("v_rcp_f32 %0, %1" : "=v"(r) : "v"(x)); return r;
}
__device__ __forceinline__ float sigm(float x){
    return rcp_fast(1.0f + __expf(-x));
}
__device__ __forceinline__ float tanh_f(float x){
    x = fminf(10.0f, fmaxf(-10.0f, x));
    float e = __expf(2.0f * x);
    return (e - 1.0f) * rcp_fast(e + 1.0f);
}

// 48 M-tiles of 16 rows, GATE-INTERLEAVED: tile row rho <-> (unit 4*tau+(rho>>2),
// gate rho&3).  Tiles 0-31: L1 (units 0-127 x 4 gates, K=192 over [x;h1]).
// Tiles 32-47: L2 (units 0-63 x 4 gates, K=192 over [h1;h2]).
// act (f16,256): [ x(64) | h1(128) | h2(64) ].  L1 kbase=0, L2 kbase=64.
// C/D: col=lane&15, row=(lane>>4)*4+reg  [m89] => lane's acc regs 0..3 hold
// gates i,f,g,o of unit 4*tau+kg.  Lane handles only tile sel=(lane&15)>>2
// (the 16 cols are duplicates); c-state is one scalar per lane.

__launch_bounds__(NT, 3)
__global__ void lstm_mfma(const float* __restrict__ x,
                          const float* __restrict__ Wih1, const float* __restrict__ Whh1,
                          const float* __restrict__ bih1, const float* __restrict__ bhh1,
                          const float* __restrict__ Wih2, const float* __restrict__ Whh2,
                          const float* __restrict__ bih2, const float* __restrict__ bhh2,
                          const float* __restrict__ W1,   const float* __restrict__ b1,
                          const float* __restrict__ W2,   const float* __restrict__ b2,
                          float* __restrict__ out)
{
    __shared__ __align__(16) f16 act[2][256];
    __shared__ float headbuf[32];

    const int j    = threadIdx.x;      // 0..767
    const int b    = blockIdx.x;
    const int wave = j >> 6;           // 0..11
    const int lane = j & 63;
    const int rho  = lane & 15;
    const int kg   = lane >> 4;        // 0..3
    const bool l2w = (wave >= 8);
    const int kbase = l2w ? 64 : 0;

    // ---------- one-time: A fragments (f16, interleaved rows), biases ----------
    hf8 A[4][6];
    ff4 bias[4];
    #pragma unroll
    for (int i = 0; i < 4; ++i){
        const int tau = 4*wave + i;
        #pragma unroll
        for (int kt = 0; kt < 6; ++kt){
            const int k = 32*kt + kg*8;
            const float* src;
            if (!l2w){
                const int R = (rho & 3)*128 + 4*tau + (rho >> 2);
                src = (k < 64) ? (Wih1 + R*64 + k) : (Whh1 + R*128 + (k - 64));
            } else {
                const int R = (rho & 3)*64 + 4*(tau - 32) + (rho >> 2);
                src = (k < 128) ? (Wih2 + R*128 + k) : (Whh2 + R*64 + (k - 128));
            }
            float4 v0 = *(const float4*)src;
            float4 v1 = *(const float4*)(src + 4);
            hf8 a;
            a[0]=(f16)v0.x; a[1]=(f16)v0.y; a[2]=(f16)v0.z; a[3]=(f16)v0.w;
            a[4]=(f16)v1.x; a[5]=(f16)v1.y; a[6]=(f16)v1.z; a[7]=(f16)v1.w;
            A[i][kt] = a;
        }
        if (!l2w){
            #pragma unroll
            for (int r = 0; r < 4; ++r){
                const int R = r*128 + 4*tau + kg;
                bias[i][r] = bih1[R] + bhh1[R];
            }
        } else {
            #pragma unroll
            for (int r = 0; r < 4; ++r){
                const int R = r*64 + 4*(tau - 32) + kg;
                bias[i][r] = bih2[R] + bhh2[R];
            }
        }
    }

    // activation ownership: lane handles tile sel, unit myU of its layer
    const int  sel    = rho >> 2;                       // 0..3
    const int  myU    = 4*(4*wave + sel - (l2w ? 32 : 0)) + kg;
    const int  dstoff = l2w ? (192 + myU) : (II + myU); // h slot in act
    const bool writer = ((lane & 3) == 0);
    float c = 0.0f;

    const float* xb = x + (size_t)b * TT * II;

    if (j < II)              act[0][j] = (f16)xb[j];    // x_0
    else if (j < 256)        act[0][j] = (f16)0.0f;     // h1 = h2 = 0
    __syncthreads();

    int cur = 0;
    for (int t = 0; t < TT; ++t){
        const f16* Ac = act[cur];
        f16*       An = act[cur ^ 1];

        // wave 8 prefetches x_{t+1} (load issued before MFMA, consumed after)
        float xn = 0.0f;
        if (wave == 8){
            int tn = (t + 1 < TT) ? (t + 1) : (TT - 1);
            xn = xb[tn*II + lane];
        }

        // ---- MFMA: preacts for L1(step t) / L2(step t-1) ----
        ff4 a0 = bias[0], a1 = bias[1], a2 = bias[2], a3 = bias[3];
        #pragma unroll
        for (int kt = 0; kt < 6; ++kt){
            hf8 bf = *(const hf8*)(Ac + kbase + 32*kt + kg*8);
            a0 = __builtin_amdgcn_mfma_f32_16x16x32_f16(A[0][kt], bf, a0, 0, 0, 0);
            a1 = __builtin_amdgcn_mfma_f32_16x16x32_f16(A[1][kt], bf, a1, 0, 0, 0);
            a2 = __builtin_amdgcn_mfma_f32_16x16x32_f16(A[2][kt], bf, a2, 0, 0, 0);
            a3 = __builtin_amdgcn_mfma_f32_16x16x32_f16(A[3][kt], bf, a3, 0, 0, 0);
        }

        // ---- in-lane activation for this lane's unit ----
        ff4 a = (sel >= 2) ? ((sel & 1) ? a3 : a2) : ((sel & 1) ? a1 : a0);
        float hv;
        if (l2w && t == 0){
            hv = 0.0f;                       // h2_{-1} = 0, c2 untouched
        } else {
            float ig = sigm(a[0]);
            float fg = sigm(a[1]);
            float gg = tanh_f(a[2]);
            float og = sigm(a[3]);
            c  = fg*c + ig*gg;
            hv = og * tanh_f(c);
        }
        if (writer)    An[dstoff] = (f16)hv;
        if (wave == 8) An[lane]   = (f16)xn;   // publish x_{t+1}
        __syncthreads();
        cur ^= 1;
    }

    // ---- epilogue: L2 step TT-1 (h1_{TT-1}, h2_{TT-2} are in act[cur]) ----
    {
        const f16* Ac = act[cur];
        f16*       An = act[cur ^ 1];
        if (l2w){
            ff4 a0 = bias[0], a1 = bias[1], a2 = bias[2], a3 = bias[3];
            #pragma unroll
            for (int kt = 0; kt < 6; ++kt){
                hf8 bf = *(const hf8*)(Ac + kbase + 32*kt + kg*8);
                a0 = __builtin_amdgcn_mfma_f32_16x16x32_f16(A[0][kt], bf, a0, 0, 0, 0);
                a1 = __builtin_amdgcn_mfma_f32_16x16x32_f16(A[1][kt], bf, a1, 0, 0, 0);
                a2 = __builtin_amdgcn_mfma_f32_16x16x32_f16(A[2][kt], bf, a2, 0, 0, 0);
                a3 = __builtin_amdgcn_mfma_f32_16x16x32_f16(A[3][kt], bf, a3, 0, 0, 0);
            }
            ff4 a = (sel >= 2) ? ((sel & 1) ? a3 : a2) : ((sel & 1) ? a1 : a0);
            float ig = sigm(a[0]);
            float fg = sigm(a[1]);
            float gg = tanh_f(a[2]);
            float og = sigm(a[3]);
            c = fg*c + ig*gg;
            float hv = og * tanh_f(c);
            if (writer) An[dstoff] = (f16)hv;
        }
    }
    __syncthreads();

    // ---- MLP head (h2 final is in act[cur^1][192..256)) ----
    {
        const f16* hf = act[cur ^ 1] + 192;
        if (j < 32){
            float a = b1[j];
            const float* w = W1 + j*64;
            #pragma unroll
            for (int k = 0; k < 64; ++k) a = fmaf(w[k], (float)hf[k], a);
            headbuf[j] = sigm(a);
        }
    }
    __syncthreads();
    if (j == 0){
        float a = b2[0];
        #pragma unroll
        for (int k = 0; k < 32; ++k) a = fmaf(W2[k], headbuf[k], a);
        out[b] = sigm(a);
    }
}

extern "C" void kernel_launch(void* const* d_in, const int* in_sizes, int n_in,
                              void* d_out, int out_size, void* d_ws, size_t ws_size,
                              hipStream_t stream)
{
    (void)in_sizes; (void)n_in; (void)d_ws; (void)ws_size; (void)out_size;
    lstm_mfma<<<NB, NT, 0, stream>>>(
        (const float*)d_in[0],
        (const float*)d_in[1], (const float*)d_in[2],
        (const float*)d_in[3], (const float*)d_in[4],
        (const float*)d_in[5], (const float*)d_in[6],
        (const float*)d_in[7], (const float*)d_in[8],
        (const float*)d_in[9], (const float*)d_in[10],
        (const float*)d_in[11], (const float*)d_in[12],
        (float*)d_out);
}